// Round 15
// baseline (362.543 us; speedup 1.0000x reference)
//
#include <hip/hip_runtime.h>

// Problem constants
#define CDIM 256        // token_size (channels)
#define CB   4096       // codebook size
#define HW   1024       // 32*32
#define NTOK 32768      // tokens
#define NELEM 8388608   // 32*256*32*32
#define MARGIN 3.5e-4f  // screen margin; worst-case need ~2e-4 (13-sigma bf16 tail)
#define OVCAP 64        // overflow slots/token; lambda~11.3 -> P(>64) ~ 0 (r12 lesson)

typedef float f32x4 __attribute__((ext_vector_type(4)));
typedef short bf16x8 __attribute__((ext_vector_type(8)));
typedef unsigned int u32;
typedef unsigned long long u64;

__device__ __forceinline__ unsigned short f2bf(float x) {   // RNE fp32->bf16
    u32 b = __float_as_uint(x);
    return (unsigned short)((b + 0x7fffu + ((b >> 16) & 1u)) >> 16);
}
// order-preserving float <-> uint
__device__ __forceinline__ u32 fenc(float f) {
    u32 b = __float_as_uint(f);
    return (b & 0x80000000u) ? ~b : (b | 0x80000000u);
}
__device__ __forceinline__ float fdec(u32 u) {
    return __uint_as_float((u & 0x80000000u) ? (u & 0x7fffffffu) : ~u);
}
__device__ __forceinline__ u64 shfl_xor_u64(u64 v, int s) {
    u32 lo = __shfl_xor((u32)v, s);
    u32 hi = __shfl_xor((u32)(v >> 32), s);
    return ((u64)hi << 32) | lo;
}
// async global->LDS, 16B per lane; lds dest = wave-uniform base + lane*16
__device__ __forceinline__ void gl_lds16(const void* g, void* l) {
    __builtin_amdgcn_global_load_lds(
        (const __attribute__((address_space(1))) u32*)g,
        (__attribute__((address_space(3))) u32*)l, 16, 0, 0);
}

// LESSONS (r9-r14): GEMM epilogue: single-pass, barrier-free, hot-path atomic-
// free, acc dying per-iteration. OVCAP needs 5x headroom over lambda~11.3 (r12).
// No single-address atomicAdd per wave (r13: 32k same-address atomics = 423 us).
// r14: k3 rewritten to 256-thread reduction but launched with 1 thread -> loss
// summed 1/256 of tokens. ALWAYS re-check launch dims after reshaping a kernel.

// ---------------- k0e: codebook norms + packed/swizzled bf16 codebook ----------------
// (2 threads/code, linear 128-ch halves; do NOT reorder the summation —
//  enorm2 enters the reference rounding chain.)
__global__ __launch_bounds__(256) void k0e(const float* __restrict__ emb,
                                           float* __restrict__ enorm2,
                                           unsigned short* __restrict__ e_hip) {
    const int cg = blockIdx.x;                 // grid = 32
    const int tid = threadIdx.x;
    const int code_l = tid >> 1;               // 2 threads per code
    const int code = cg * 128 + code_l;
    float s = 0.f;
#pragma unroll
    for (int kb = 0; kb < 4; ++kb) {
        const int c0 = (tid & 1) * 128 + kb * 32;
        const int kc = c0 >> 5;
        __align__(16) unsigned short tmp[32];
#pragma unroll
        for (int q = 0; q < 8; ++q) {
            float4 v = *(const float4*)(emb + (size_t)code * CDIM + c0 + 4 * q);
            s += v.x * v.x + v.y * v.y + v.z * v.z + v.w * v.w;
            tmp[4 * q + 0] = f2bf(v.x); tmp[4 * q + 1] = f2bf(v.y);
            tmp[4 * q + 2] = f2bf(v.z); tmp[4 * q + 3] = f2bf(v.w);
        }
        uint4* dst4 = (uint4*)(e_hip + (((size_t)(cg * 8 + kc) * 128 + code_l) * 32));
#pragma unroll
        for (int q = 0; q < 4; ++q)
            dst4[q ^ (code_l & 3)] = *(uint4*)&tmp[8 * q];   // XOR-swizzled quad chunks
    }
    s += __shfl_xor(s, 1);
    if ((tid & 1) == 0) enorm2[code] = s;
}

// ---------------- p0: transpose z -> zT fp32 + packed/swizzled bf16 z + zn/ovcnt ----------------
__global__ __launch_bounds__(256) void p0(const float* __restrict__ z,
                                          float* __restrict__ zT,
                                          unsigned short* __restrict__ z_hip,
                                          float* __restrict__ zn,
                                          u32* __restrict__ ovcnt) {
    __shared__ float T[32][132];
    const int rg = blockIdx.x;                 // grid = 256 (128 tokens each)
    const int tid = threadIdx.x;
    const int b = (rg * 128) >> 10, hw0 = (rg * 128) & 1023;
    const float* zb = z + (size_t)b * (CDIM * HW) + hw0;
    const int tt = tid >> 1, h = (tid & 1) * 16;   // token, channel-half within chunk
    const int q0 = h >> 3;                         // first quad handled (0 or 2)
    float zsq = 0.f;
    for (int kc = 0; kc < 8; ++kc) {
        const int c0 = kc * 32;
        __syncthreads();
#pragma unroll
        for (int p = 0; p < 16; ++p) {
            const int c = p * 2 + (tid >> 7);
            T[c][tid & 127] = zb[(size_t)(c0 + c) * HW + (tid & 127)];
        }
        __syncthreads();
        float* dstT = zT + (size_t)(rg * 128 + tt) * CDIM + c0 + h;
        __align__(16) unsigned short us[16];
#pragma unroll
        for (int q = 0; q < 4; ++q) {
            float4 v;
            v.x = T[h + 4 * q + 0][tt]; v.y = T[h + 4 * q + 1][tt];
            v.z = T[h + 4 * q + 2][tt]; v.w = T[h + 4 * q + 3][tt];
            ((float4*)dstT)[q] = v;
            zsq += v.x * v.x + v.y * v.y + v.z * v.z + v.w * v.w;
            us[4 * q + 0] = f2bf(v.x); us[4 * q + 1] = f2bf(v.y);
            us[4 * q + 2] = f2bf(v.z); us[4 * q + 3] = f2bf(v.w);
        }
        uint4* d4 = (uint4*)(z_hip + (((size_t)(rg * 8 + kc) * 128 + tt) * 32));
        d4[q0 ^ (tt & 3)]       = *(uint4*)&us[0];   // XOR-swizzled quad chunks
        d4[(q0 + 1) ^ (tt & 3)] = *(uint4*)&us[8];
    }
    zsq += __shfl_xor(zsq, 1);     // fp32 sum order arbitrary: argmin translation-invariant
    if ((tid & 1) == 0) {
        const int t = rg * 128 + tt;
        zn[t] = zsq; ovcnt[t] = 0u;
    }
}

// Tile: 128 tokens x 128 codes, K=256 in 8 chunks of 32. 4 waves in 2x2; each wave
// 4x4 grid of 16x16x32 MFMAs. A[m=lane&15][k=quad*8+j]; B as B^T rows (n=lane&15);
// C: col=lane&15, row=quad*4+reg (m89-verified). Staging via global_load_lds w=16.

// ---------------- p1: bf16 MFMA screen -> per-(token, wave-half) min slot + rare overflow ----
__global__ __launch_bounds__(256) void p1(const unsigned short* __restrict__ z_hip,
                                          const unsigned short* __restrict__ e_hip,
                                          const float* __restrict__ enorm2,
                                          u64* __restrict__ cand,
                                          u32* __restrict__ ovcnt,
                                          u64* __restrict__ ovslot) {
    __shared__ __align__(16) unsigned short As[128 * 32];
    __shared__ __align__(16) unsigned short Bs[128 * 32];
    const int bid = blockIdx.x;                // grid = 8192
    const int rg = bid >> 5, cg = bid & 31;    // consecutive blocks share A-tile (L2)
    const int tid = threadIdx.x;
    const int w = tid >> 6, lane = tid & 63;
    const int quad = lane >> 4, l15 = lane & 15;
    const int rowoff = (w >> 1) * 64, coloff = (w & 1) * 64;
    const int swz = (quad ^ (l15 & 3)) * 8;    // de-swizzle for fragment reads

    f32x4 acc[4][4];
#pragma unroll
    for (int i = 0; i < 4; ++i)
#pragma unroll
        for (int j = 0; j < 4; ++j)
#pragma unroll
            for (int e = 0; e < 4; ++e) acc[i][j][e] = 0.f;

    const char* gA = (const char*)z_hip + ((size_t)rg << 16) + w * 2048 + lane * 16;
    const char* gB = (const char*)e_hip + ((size_t)cg << 16) + w * 2048 + lane * 16;
    char* lA = (char*)As + w * 2048;           // wave-uniform LDS base
    char* lB = (char*)Bs + w * 2048;
    for (int kc = 0; kc < 8; ++kc) {
        __syncthreads();
        gl_lds16(gA, lA);           gl_lds16(gA + 1024, lA + 1024);
        gl_lds16(gB, lB);           gl_lds16(gB + 1024, lB + 1024);
        gA += 8192; gB += 8192;
        __syncthreads();
        bf16x8 af[4], bfr[4];
#pragma unroll
        for (int ni = 0; ni < 4; ++ni)
            bfr[ni] = *(const bf16x8*)&Bs[(coloff + ni * 16 + l15) * 32 + swz];
#pragma unroll
        for (int mi = 0; mi < 4; ++mi)
            af[mi] = *(const bf16x8*)&As[(rowoff + mi * 16 + l15) * 32 + swz];
#pragma unroll
        for (int mi = 0; mi < 4; ++mi)
#pragma unroll
            for (int ni = 0; ni < 4; ++ni)
                acc[mi][ni] = __builtin_amdgcn_mfma_f32_16x16x32_bf16(
                    af[mi], bfr[ni], acc[mi][ni], 0, 0, 0);
    }
    // ---- single-pass, barrier-free epilogue ----
    float en[4];
#pragma unroll
    for (int ni = 0; ni < 4; ++ni) en[ni] = enorm2[cg * 128 + coloff + ni * 16 + l15];
    const int slot = cg * 2 + (w & 1);
#pragma unroll
    for (int mi = 0; mi < 4; ++mi) {
#pragma unroll
        for (int r = 0; r < 4; ++r) {
            const int row = rowoff + mi * 16 + quad * 4 + r;
            const int t = rg * 128 + row;
            float dv[4];
            u64 best = ~0ull;
#pragma unroll
            for (int ni = 0; ni < 4; ++ni) {
                dv[ni] = en[ni] - 2.0f * acc[mi][ni][r];
                const u64 p = ((u64)fenc(dv[ni]) << 32)
                            | (u32)(cg * 128 + coloff + ni * 16 + l15);
                best = p < best ? p : best;
            }
#pragma unroll
            for (int s = 1; s < 16; s <<= 1) {       // butterfly: all 16 lanes get min
                const u64 o = shfl_xor_u64(best, s);
                best = o < best ? o : best;
            }
            if (l15 == 0) cand[((size_t)t << 6) + slot] = best;   // plain 8B store
            const float thr = fdec((u32)(best >> 32)) + MARGIN;
#pragma unroll
            for (int ni = 0; ni < 4; ++ni) {         // rare-path extras
                if (dv[ni] <= thr) {
                    const u64 p = ((u64)fenc(dv[ni]) << 32)
                                | (u32)(cg * 128 + coloff + ni * 16 + l15);
                    if (p != best) {
                        const u32 pos = atomicAdd(&ovcnt[t], 1u);
                        if (pos < (u32)OVCAP) ovslot[(size_t)t * OVCAP + pos] = p;
                    }
                }
            }
        }
    }
}

// ---------------- k5: gmin from 64 slots, filter, exact fp32 rescore; dmin via plain store ----
__global__ __launch_bounds__(256) void k5(const float* __restrict__ zT,
                                          const float* __restrict__ emb,
                                          const float* __restrict__ enorm2,
                                          const float* __restrict__ zn,
                                          const u64* __restrict__ cand,
                                          const u32* __restrict__ ovcnt,
                                          const u64* __restrict__ ovslot,
                                          float* __restrict__ idxf,
                                          float* __restrict__ dmin) {
    const int t = (blockIdx.x * 256 + threadIdx.x) >> 6;   // wave per token, grid = 8192
    const int lane = threadIdx.x & 63;
    const u64 pkv = cand[((size_t)t << 6) + lane];         // coalesced 512B/wave
    u64 g = pkv;
#pragma unroll
    for (int s = 1; s < 64; s <<= 1) {
        const u64 o = shfl_xor_u64(g, s);
        g = o < g ? o : g;
    }
    const float thr = fdec((u32)(g >> 32)) + MARGIN;       // gmin + MARGIN
    const float4 za = ((const float4*)(zT + (size_t)t * CDIM))[lane];
    const float znv = zn[t];
    float bdv = 1e30f; int bk = 0x7fffffff;
    unsigned long long q = __ballot(fdec((u32)(pkv >> 32)) <= thr);  // slot survivors
    while (q) {
        const int i = __ffsll(q) - 1; q &= q - 1;
        const int k = __shfl((int)(u32)pkv, i);
        const float4 ea = ((const float4*)(emb + (size_t)k * CDIM))[lane];
        float p = za.x * ea.x + za.y * ea.y + za.z * ea.z + za.w * ea.w;
#pragma unroll
        for (int s = 1; s < 64; s <<= 1) p += __shfl_xor(p, s);
        const float t1 = znv + enorm2[k];         // fl(zn + en)  — reference chain
        const float d = t1 - 2.0f * p;            // fl(t1 - 2 dot)
        if (d < bdv || (d == bdv && k < bk)) { bdv = d; bk = k; }
    }
    u32 n = ovcnt[t]; if (n > (u32)OVCAP) n = (u32)OVCAP;  // overflow survivors (rare)
    for (u32 i = 0; i < n; ++i) {
        const u64 ov = ovslot[(size_t)t * OVCAP + i];      // wave-uniform broadcast load
        if (!(fdec((u32)(ov >> 32)) <= thr)) continue;
        const int k = (int)(u32)ov;
        const float4 ea = ((const float4*)(emb + (size_t)k * CDIM))[lane];
        float p = za.x * ea.x + za.y * ea.y + za.z * ea.z + za.w * ea.w;
#pragma unroll
        for (int s = 1; s < 64; s <<= 1) p += __shfl_xor(p, s);
        const float t1 = znv + enorm2[k];
        const float d = t1 - 2.0f * p;
        if (d < bdv || (d == bdv && k < bk)) { bdv = d; bk = k; }
    }
    if (lane == 0) {
        idxf[t] = (float)bk;
        dmin[t] = bdv;        // plain coalesced store; k3 reduces (NO atomics — r13 lesson)
    }
}

// ---------------- k2: pure scatter z_q = emb[idx] ----------------
__global__ __launch_bounds__(256) void k2(const float* __restrict__ emb,
                                          const float* __restrict__ idxf,
                                          float* __restrict__ zq) {
    __shared__ int ks[64];
    const int tid = threadIdx.x;
    const int tok0 = blockIdx.x * 64;          // grid = 512
    const int b = tok0 >> 10, hw0 = tok0 & 1023;
    if (tid < 64) ks[tid] = (int)idxf[tok0 + tid];
    __syncthreads();
    const int t4 = (tid & 15) * 4;
    const int ka = ks[t4], kb = ks[t4 + 1], kc = ks[t4 + 2], kd = ks[t4 + 3];
    float* outb = zq + (size_t)b * (CDIM * HW) + hw0 + t4;
    int c = tid >> 4;
#pragma unroll
    for (int p = 0; p < 16; ++p, c += 16) {
        float4 v;
        v.x = emb[(size_t)ka * CDIM + c];
        v.y = emb[(size_t)kb * CDIM + c];
        v.z = emb[(size_t)kc * CDIM + c];
        v.w = emb[(size_t)kd * CDIM + c];
        *(float4*)(outb + (size_t)c * HW) = v;   // coalesced float4 store
    }
}

// ---------------- k3: reduce dmin -> the three loss scalars (1 block x 256 thr, no atomics) ----
__global__ __launch_bounds__(256) void k3(const float* __restrict__ dmin,
                                          float* __restrict__ out) {
    __shared__ float red[256];
    const int tid = threadIdx.x;
    const float4* d4 = (const float4*)dmin;
    float s = 0.f;
    for (int i = tid; i < NTOK / 4; i += 256) {    // 32 float4 loads/thread
        const float4 v = d4[i];
        s += (v.x + v.y) + (v.z + v.w);
    }
    red[tid] = s;
    __syncthreads();
    for (int o = 128; o > 0; o >>= 1) {
        if (tid < o) red[tid] += red[tid + o];
        __syncthreads();
    }
    if (tid == 0) {
        const float mse = red[0] / (float)NELEM;
        out[0] = 1.25f * mse;   // loss
        out[1] = 0.25f * mse;   // commitment_loss
        out[2] = mse;           // codebook_loss
    }
}

extern "C" void kernel_launch(void* const* d_in, const int* in_sizes, int n_in,
                              void* d_out, int out_size, void* d_ws, size_t ws_size,
                              hipStream_t stream) {
    const float* z   = (const float*)d_in[0];   // [32,256,32,32]
    const float* emb = (const float*)d_in[1];   // [4096,256]
    float* out = (float*)d_out;                 // zq | 3 scalars | idx (as f32)
    char* w = (char*)d_ws;

    float* zn     = (float*)w;                       w += NTOK * 4;
    float* enorm2 = (float*)w;                       w += CB * 4;
    u32*   ovcnt  = (u32*)w;                         w += NTOK * 4;
    float* dmin   = (float*)w;                       w += NTOK * 4;
    float* zT     = (float*)w;                       w += (size_t)NTOK * CDIM * 4;
    unsigned short* z_hip = (unsigned short*)w;      w += (size_t)NTOK * CDIM * 2;
    unsigned short* e_hip = (unsigned short*)w;      w += (size_t)CB * CDIM * 2;
    u64*   cand   = (u64*)w;                         w += (size_t)NTOK * 64 * 8;
    u64*   ovslot = (u64*)w;                         w += (size_t)NTOK * OVCAP * 8;
    float* idxf = out + NELEM + 3;

    hipLaunchKernelGGL(k0e, dim3(CB / 128),   dim3(256), 0, stream, emb, enorm2, e_hip);
    hipLaunchKernelGGL(p0,  dim3(NTOK / 128), dim3(256), 0, stream, z, zT, z_hip, zn, ovcnt);
    hipLaunchKernelGGL(p1,  dim3((NTOK / 128) * (CB / 128)), dim3(256), 0, stream,
                       z_hip, e_hip, enorm2, cand, ovcnt, ovslot);
    hipLaunchKernelGGL(k5,  dim3(NTOK / 4),   dim3(256), 0, stream,
                       zT, emb, enorm2, zn, cand, ovcnt, ovslot, idxf, dmin);
    hipLaunchKernelGGL(k2,  dim3(NTOK / 64),  dim3(256), 0, stream, emb, idxf, out);
    hipLaunchKernelGGL(k3,  dim3(1), dim3(256), 0, stream, dmin, out + NELEM);  // r14 fix: 256 threads
}

// Round 16
// 356.067 us; speedup vs baseline: 1.0182x; 1.0182x over previous
//
#include <hip/hip_runtime.h>

// Problem constants
#define CDIM 256        // token_size (channels)
#define CB   4096       // codebook size
#define HW   1024       // 32*32
#define NTOK 32768      // tokens
#define NELEM 8388608   // 32*256*32*32
#define MARGIN 3.5e-4f  // screen margin; worst-case need ~2e-4 (13-sigma bf16 tail)
#define OVCAP 64        // overflow slots/token; lambda~11.3 -> P(>64) ~ 0 (r12 lesson)

typedef float f32x4 __attribute__((ext_vector_type(4)));
typedef short bf16x8 __attribute__((ext_vector_type(8)));
typedef unsigned int u32;
typedef unsigned long long u64;

__device__ __forceinline__ unsigned short f2bf(float x) {   // RNE fp32->bf16
    u32 b = __float_as_uint(x);
    return (unsigned short)((b + 0x7fffu + ((b >> 16) & 1u)) >> 16);
}
// order-preserving float <-> uint
__device__ __forceinline__ u32 fenc(float f) {
    u32 b = __float_as_uint(f);
    return (b & 0x80000000u) ? ~b : (b | 0x80000000u);
}
__device__ __forceinline__ float fdec(u32 u) {
    return __uint_as_float((u & 0x80000000u) ? (u & 0x7fffffffu) : ~u);
}
__device__ __forceinline__ u64 shfl_xor_u64(u64 v, int s) {
    u32 lo = __shfl_xor((u32)v, s);
    u32 hi = __shfl_xor((u32)(v >> 32), s);
    return ((u64)hi << 32) | lo;
}
// async global->LDS, 16B per lane; lds dest = wave-uniform base + lane*16
__device__ __forceinline__ void gl_lds16(const void* g, void* l) {
    __builtin_amdgcn_global_load_lds(
        (const __attribute__((address_space(1))) u32*)g,
        (__attribute__((address_space(3))) u32*)l, 16, 0, 0);
}

// LESSONS (r9-r15): GEMM epilogue: single-pass, barrier-free, hot-path atomic-
// free, acc dying per-iteration. OVCAP 5x headroom over lambda~11.3 (r12).
// No single-address atomicAdd per wave (r13). Re-check launch dims after any
// kernel reshape (r14). u64 butterflies ~= GEMM cost (r11) -> float butterfly
// + ballot-elected single-lane u64 pack (this round).

// ---------------- prep: fused p0 (blocks 0..255) + k0e (blocks 256..287) ----------------
__global__ __launch_bounds__(256) void prep(const float* __restrict__ z,
                                            const float* __restrict__ emb,
                                            float* __restrict__ zT,
                                            unsigned short* __restrict__ z_hip,
                                            float* __restrict__ zn,
                                            u32* __restrict__ ovcnt,
                                            float* __restrict__ enorm2,
                                            unsigned short* __restrict__ e_hip,
                                            u32* __restrict__ cnt2) {
    __shared__ float T[32][132];
    const int tid = threadIdx.x;
    if (blockIdx.x >= 256) {
        // ---- k0e role: codebook norms + packed/swizzled bf16 codebook ----
        // (2 threads/code, linear 128-ch halves; summation order is part of the
        //  reference rounding chain — do not reorder.)
        const int cg = blockIdx.x - 256;           // 0..31
        const int code_l = tid >> 1;
        const int code = cg * 128 + code_l;
        float s = 0.f;
#pragma unroll
        for (int kb = 0; kb < 4; ++kb) {
            const int c0 = (tid & 1) * 128 + kb * 32;
            const int kc = c0 >> 5;
            __align__(16) unsigned short tmp[32];
#pragma unroll
            for (int q = 0; q < 8; ++q) {
                float4 v = *(const float4*)(emb + (size_t)code * CDIM + c0 + 4 * q);
                s += v.x * v.x + v.y * v.y + v.z * v.z + v.w * v.w;
                tmp[4 * q + 0] = f2bf(v.x); tmp[4 * q + 1] = f2bf(v.y);
                tmp[4 * q + 2] = f2bf(v.z); tmp[4 * q + 3] = f2bf(v.w);
            }
            uint4* dst4 = (uint4*)(e_hip + (((size_t)(cg * 8 + kc) * 128 + code_l) * 32));
#pragma unroll
            for (int q = 0; q < 4; ++q)
                dst4[q ^ (code_l & 3)] = *(uint4*)&tmp[8 * q];   // XOR-swizzled quads
        }
        s += __shfl_xor(s, 1);
        if ((tid & 1) == 0) enorm2[code] = s;
        if (cg == 0 && tid == 0) *cnt2 = 0u;       // k2 last-block election counter
        return;
    }
    // ---- p0 role: transpose z -> zT fp32 + packed/swizzled bf16 z + zn/ovcnt ----
    const int rg = blockIdx.x;
    const int b = (rg * 128) >> 10, hw0 = (rg * 128) & 1023;
    const float* zb = z + (size_t)b * (CDIM * HW) + hw0;
    const int tt = tid >> 1, h = (tid & 1) * 16;   // token, channel-half within chunk
    const int q0 = h >> 3;                         // first quad handled (0 or 2)
    float zsq = 0.f;
    for (int kc = 0; kc < 8; ++kc) {
        const int c0 = kc * 32;
        __syncthreads();
#pragma unroll
        for (int p = 0; p < 16; ++p) {
            const int c = p * 2 + (tid >> 7);
            T[c][tid & 127] = zb[(size_t)(c0 + c) * HW + (tid & 127)];
        }
        __syncthreads();
        float* dstT = zT + (size_t)(rg * 128 + tt) * CDIM + c0 + h;
        __align__(16) unsigned short us[16];
#pragma unroll
        for (int q = 0; q < 4; ++q) {
            float4 v;
            v.x = T[h + 4 * q + 0][tt]; v.y = T[h + 4 * q + 1][tt];
            v.z = T[h + 4 * q + 2][tt]; v.w = T[h + 4 * q + 3][tt];
            ((float4*)dstT)[q] = v;
            zsq += v.x * v.x + v.y * v.y + v.z * v.z + v.w * v.w;
            us[4 * q + 0] = f2bf(v.x); us[4 * q + 1] = f2bf(v.y);
            us[4 * q + 2] = f2bf(v.z); us[4 * q + 3] = f2bf(v.w);
        }
        uint4* d4 = (uint4*)(z_hip + (((size_t)(rg * 8 + kc) * 128 + tt) * 32));
        d4[q0 ^ (tt & 3)]       = *(uint4*)&us[0];   // XOR-swizzled quads
        d4[(q0 + 1) ^ (tt & 3)] = *(uint4*)&us[8];
    }
    zsq += __shfl_xor(zsq, 1);     // fp32 sum order arbitrary: argmin translation-invariant
    if ((tid & 1) == 0) {
        const int t = rg * 128 + tt;
        zn[t] = zsq; ovcnt[t] = 0u;
    }
}

// Tile: 128 tokens x 128 codes, K=256 in 8 chunks of 32. 4 waves in 2x2; each wave
// 4x4 grid of 16x16x32 MFMAs. A[m=lane&15][k=quad*8+j]; B as B^T rows (n=lane&15);
// C: col=lane&15, row=quad*4+reg (m89-verified). Staging via global_load_lds w=16.

// ---------------- p1: bf16 MFMA screen -> per-(token, wave-half) min slot + rare overflow ----
// Epilogue: per row, float min over 4 ni + 4-step float butterfly; ballot elects
// lowest-l15 matching lane, which alone builds the u64 (d,k) slot pack. Ties/extras
// d<=halfmin+MARGIN go to the overflow pool (duplicates harmless; k5 rescores).
__global__ __launch_bounds__(256) void p1(const unsigned short* __restrict__ z_hip,
                                          const unsigned short* __restrict__ e_hip,
                                          const float* __restrict__ enorm2,
                                          u64* __restrict__ cand,
                                          u32* __restrict__ ovcnt,
                                          u64* __restrict__ ovslot) {
    __shared__ __align__(16) unsigned short As[128 * 32];
    __shared__ __align__(16) unsigned short Bs[128 * 32];
    const int bid = blockIdx.x;                // grid = 8192
    const int rg = bid >> 5, cg = bid & 31;    // consecutive blocks share A-tile (L2)
    const int tid = threadIdx.x;
    const int w = tid >> 6, lane = tid & 63;
    const int quad = lane >> 4, l15 = lane & 15;
    const int rowoff = (w >> 1) * 64, coloff = (w & 1) * 64;
    const int swz = (quad ^ (l15 & 3)) * 8;    // de-swizzle for fragment reads

    f32x4 acc[4][4];
#pragma unroll
    for (int i = 0; i < 4; ++i)
#pragma unroll
        for (int j = 0; j < 4; ++j)
#pragma unroll
            for (int e = 0; e < 4; ++e) acc[i][j][e] = 0.f;

    const char* gA = (const char*)z_hip + ((size_t)rg << 16) + w * 2048 + lane * 16;
    const char* gB = (const char*)e_hip + ((size_t)cg << 16) + w * 2048 + lane * 16;
    char* lA = (char*)As + w * 2048;           // wave-uniform LDS base
    char* lB = (char*)Bs + w * 2048;
    for (int kc = 0; kc < 8; ++kc) {
        __syncthreads();
        gl_lds16(gA, lA);           gl_lds16(gA + 1024, lA + 1024);
        gl_lds16(gB, lB);           gl_lds16(gB + 1024, lB + 1024);
        gA += 8192; gB += 8192;
        __syncthreads();
        bf16x8 af[4], bfr[4];
#pragma unroll
        for (int ni = 0; ni < 4; ++ni)
            bfr[ni] = *(const bf16x8*)&Bs[(coloff + ni * 16 + l15) * 32 + swz];
#pragma unroll
        for (int mi = 0; mi < 4; ++mi)
            af[mi] = *(const bf16x8*)&As[(rowoff + mi * 16 + l15) * 32 + swz];
#pragma unroll
        for (int mi = 0; mi < 4; ++mi)
#pragma unroll
            for (int ni = 0; ni < 4; ++ni)
                acc[mi][ni] = __builtin_amdgcn_mfma_f32_16x16x32_bf16(
                    af[mi], bfr[ni], acc[mi][ni], 0, 0, 0);
    }
    // ---- single-pass, barrier-free epilogue (float butterfly + ballot election) ----
    float en[4];
#pragma unroll
    for (int ni = 0; ni < 4; ++ni) en[ni] = enorm2[cg * 128 + coloff + ni * 16 + l15];
    const int slot = cg * 2 + (w & 1);
#pragma unroll
    for (int mi = 0; mi < 4; ++mi) {
#pragma unroll
        for (int r = 0; r < 4; ++r) {
            const int row = rowoff + mi * 16 + quad * 4 + r;
            const int t = rg * 128 + row;
            float dv[4];
#pragma unroll
            for (int ni = 0; ni < 4; ++ni) dv[ni] = en[ni] - 2.0f * acc[mi][ni][r];
            float m = fminf(fminf(dv[0], dv[1]), fminf(dv[2], dv[3]));
            m = fminf(m, __shfl_xor(m, 1));
            m = fminf(m, __shfl_xor(m, 2));
            m = fminf(m, __shfl_xor(m, 4));
            m = fminf(m, __shfl_xor(m, 8));        // 16-lane group min (exact bits)
            const u32 myni = dv[0] == m ? 0u : dv[1] == m ? 1u
                           : dv[2] == m ? 2u : dv[3] == m ? 3u : 4u;
            const unsigned long long bal = __ballot(myni < 4u);
            const int sl = __ffs((u32)((bal >> (quad << 4)) & 0xFFFFu)) - 1;
            if (l15 == sl) {                        // elected lane stores the slot
                const u32 k = (u32)(cg * 128 + coloff + (int)myni * 16 + l15);
                cand[((size_t)t << 6) + slot] = ((u64)fenc(m) << 32) | k;
            }
            const float thr = m + MARGIN;
#pragma unroll
            for (int ni = 0; ni < 4; ++ni) {        // rare-path extras
                if (dv[ni] <= thr && !(l15 == sl && ni == (int)myni)) {
                    const u32 k = (u32)(cg * 128 + coloff + ni * 16 + l15);
                    const u32 pos = atomicAdd(&ovcnt[t], 1u);
                    if (pos < (u32)OVCAP)
                        ovslot[(size_t)t * OVCAP + pos] = ((u64)fenc(dv[ni]) << 32) | k;
                }
            }
        }
    }
}

// ---------------- k5: gmin from 64 slots, filter, exact fp32 rescore; dmin via plain store ----
__global__ __launch_bounds__(256) void k5(const float* __restrict__ zT,
                                          const float* __restrict__ emb,
                                          const float* __restrict__ enorm2,
                                          const float* __restrict__ zn,
                                          const u64* __restrict__ cand,
                                          const u32* __restrict__ ovcnt,
                                          const u64* __restrict__ ovslot,
                                          float* __restrict__ idxf,
                                          float* __restrict__ dmin) {
    const int t = (blockIdx.x * 256 + threadIdx.x) >> 6;   // wave per token, grid = 8192
    const int lane = threadIdx.x & 63;
    const u64 pkv = cand[((size_t)t << 6) + lane];         // coalesced 512B/wave
    u64 g = pkv;
#pragma unroll
    for (int s = 1; s < 64; s <<= 1) {
        const u64 o = shfl_xor_u64(g, s);
        g = o < g ? o : g;
    }
    const float thr = fdec((u32)(g >> 32)) + MARGIN;       // gmin + MARGIN
    const float4 za = ((const float4*)(zT + (size_t)t * CDIM))[lane];
    const float znv = zn[t];
    float bdv = 1e30f; int bk = 0x7fffffff;
    unsigned long long q = __ballot(fdec((u32)(pkv >> 32)) <= thr);  // slot survivors
    while (q) {
        const int i = __ffsll(q) - 1; q &= q - 1;
        const int k = __shfl((int)(u32)pkv, i);
        const float4 ea = ((const float4*)(emb + (size_t)k * CDIM))[lane];
        float p = za.x * ea.x + za.y * ea.y + za.z * ea.z + za.w * ea.w;
#pragma unroll
        for (int s = 1; s < 64; s <<= 1) p += __shfl_xor(p, s);
        const float t1 = znv + enorm2[k];         // fl(zn + en)  — reference chain
        const float d = t1 - 2.0f * p;            // fl(t1 - 2 dot)
        if (d < bdv || (d == bdv && k < bk)) { bdv = d; bk = k; }
    }
    u32 n = ovcnt[t]; if (n > (u32)OVCAP) n = (u32)OVCAP;  // overflow survivors (rare)
    for (u32 i = 0; i < n; ++i) {
        const u64 ov = ovslot[(size_t)t * OVCAP + i];      // wave-uniform broadcast load
        if (!(fdec((u32)(ov >> 32)) <= thr)) continue;
        const int k = (int)(u32)ov;
        const float4 ea = ((const float4*)(emb + (size_t)k * CDIM))[lane];
        float p = za.x * ea.x + za.y * ea.y + za.z * ea.z + za.w * ea.w;
#pragma unroll
        for (int s = 1; s < 64; s <<= 1) p += __shfl_xor(p, s);
        const float t1 = znv + enorm2[k];
        const float d = t1 - 2.0f * p;
        if (d < bdv || (d == bdv && k < bk)) { bdv = d; bk = k; }
    }
    if (lane == 0) {
        idxf[t] = (float)bk;
        dmin[t] = bdv;        // plain coalesced store (NO atomics — r13 lesson)
    }
}

// ---------------- k2: scatter z_q = emb[idx]; last block reduces dmin -> loss scalars ----------
__global__ __launch_bounds__(256) void k2(const float* __restrict__ emb,
                                          const float* __restrict__ idxf,
                                          const float* __restrict__ dmin,
                                          float* __restrict__ zq,
                                          float* __restrict__ out3,
                                          u32* __restrict__ cnt2) {
    __shared__ int ks[64];
    __shared__ float red[256];
    __shared__ int lastFlag;
    const int tid = threadIdx.x;
    const int tok0 = blockIdx.x * 64;          // grid = 512
    const int b = tok0 >> 10, hw0 = tok0 & 1023;
    if (tid < 64) ks[tid] = (int)idxf[tok0 + tid];
    __syncthreads();
    const int t4 = (tid & 15) * 4;
    const int ka = ks[t4], kb = ks[t4 + 1], kc = ks[t4 + 2], kd = ks[t4 + 3];
    float* outb = zq + (size_t)b * (CDIM * HW) + hw0 + t4;
    int c = tid >> 4;
#pragma unroll
    for (int p = 0; p < 16; ++p, c += 16) {
        float4 v;
        v.x = emb[(size_t)ka * CDIM + c];
        v.y = emb[(size_t)kb * CDIM + c];
        v.z = emb[(size_t)kc * CDIM + c];
        v.w = emb[(size_t)kd * CDIM + c];
        *(float4*)(outb + (size_t)c * HW) = v;   // coalesced float4 store
    }
    // last-block election computes the loss (dmin complete: k5 precedes in stream)
    if (tid == 0) lastFlag = (atomicAdd(cnt2, 1u) == 511u) ? 1 : 0;
    __syncthreads();
    if (lastFlag) {
        const float4* d4 = (const float4*)dmin;
        float s = 0.f;
        for (int i = tid; i < NTOK / 4; i += 256) {
            const float4 v = d4[i];
            s += (v.x + v.y) + (v.z + v.w);
        }
        red[tid] = s;
        __syncthreads();
        for (int o = 128; o > 0; o >>= 1) {
            if (tid < o) red[tid] += red[tid + o];
            __syncthreads();
        }
        if (tid == 0) {
            const float mse = red[0] / (float)NELEM;
            out3[0] = 1.25f * mse;   // loss
            out3[1] = 0.25f * mse;   // commitment_loss
            out3[2] = mse;           // codebook_loss
        }
    }
}

extern "C" void kernel_launch(void* const* d_in, const int* in_sizes, int n_in,
                              void* d_out, int out_size, void* d_ws, size_t ws_size,
                              hipStream_t stream) {
    const float* z   = (const float*)d_in[0];   // [32,256,32,32]
    const float* emb = (const float*)d_in[1];   // [4096,256]
    float* out = (float*)d_out;                 // zq | 3 scalars | idx (as f32)
    char* w = (char*)d_ws;

    float* zn     = (float*)w;                       w += NTOK * 4;
    float* enorm2 = (float*)w;                       w += CB * 4;
    u32*   ovcnt  = (u32*)w;                         w += NTOK * 4;
    float* dmin   = (float*)w;                       w += NTOK * 4;
    u32*   cnt2   = (u32*)w;                         w += 256;
    float* zT     = (float*)w;                       w += (size_t)NTOK * CDIM * 4;
    unsigned short* z_hip = (unsigned short*)w;      w += (size_t)NTOK * CDIM * 2;
    unsigned short* e_hip = (unsigned short*)w;      w += (size_t)CB * CDIM * 2;
    u64*   cand   = (u64*)w;                         w += (size_t)NTOK * 64 * 8;
    u64*   ovslot = (u64*)w;                         w += (size_t)NTOK * OVCAP * 8;
    float* idxf = out + NELEM + 3;

    hipLaunchKernelGGL(prep, dim3(256 + 32),  dim3(256), 0, stream,
                       z, emb, zT, z_hip, zn, ovcnt, enorm2, e_hip, cnt2);
    hipLaunchKernelGGL(p1,  dim3((NTOK / 128) * (CB / 128)), dim3(256), 0, stream,
                       z_hip, e_hip, enorm2, cand, ovcnt, ovslot);
    hipLaunchKernelGGL(k5,  dim3(NTOK / 4),   dim3(256), 0, stream,
                       zT, emb, enorm2, zn, cand, ovcnt, ovslot, idxf, dmin);
    hipLaunchKernelGGL(k2,  dim3(NTOK / 64),  dim3(256), 0, stream,
                       emb, idxf, dmin, out, out + NELEM, cnt2);
}